// Round 1
// baseline (755.900 us; speedup 1.0000x reference)
//
#include <hip/hip_runtime.h>
#include <math.h>

#define B_DIM 2048
#define D_DIM 512
#define F_DIM 16384
#define K_TOP 3
#define NTILE (F_DIM / 128)   // 128 column tiles

// lexicographic "better": larger value wins; tie -> lower index (lax.top_k semantics)
__device__ __forceinline__ bool better(float v, int c, float w, int j) {
    return (v > w) || (v == w && c < j);
}

__device__ __forceinline__ void ins3(float v, int c,
    float& v0, int& i0, float& v1, int& i1, float& v2, int& i2)
{
    if (!better(v, c, v2, i2)) return;
    if (better(v, c, v1, i1)) {
        v2 = v1; i2 = i1;
        if (better(v, c, v0, i0)) { v1 = v0; i1 = i0; v0 = v; i0 = c; }
        else { v1 = v; i1 = c; }
    } else { v2 = v; i2 = c; }
}

// ---------------------------------------------------------------------------
// Kernel 1: pre = x @ We^T + be, fused per-(row, 128-col-tile) top-3 partials.
// 128x128 C-tile, BK=8, 256 threads, 8x8 per thread.
// ---------------------------------------------------------------------------
__global__ __launch_bounds__(256) void enc_topk_kernel(
    const float* __restrict__ x, const float* __restrict__ We,
    const float* __restrict__ be,
    float* __restrict__ pvals, int* __restrict__ pidx)
{
    __shared__ float As[8][128];
    __shared__ float Bs[8][128];
    const int t = threadIdx.x;
    const int bm0 = blockIdx.y << 7;
    const int fn0 = blockIdx.x << 7;
    const int tm = t >> 4;        // 0..15
    const int tn = t & 15;        // 0..15
    const int lr = t >> 1;        // 0..127
    const int lc = (t & 1) << 2;  // 0 or 4

    float acc[8][8];
#pragma unroll
    for (int i = 0; i < 8; ++i)
#pragma unroll
        for (int j = 0; j < 8; ++j) acc[i][j] = 0.f;

    const float* xp = x + (size_t)(bm0 + lr) * D_DIM + lc;
    const float* wp = We + (size_t)(fn0 + lr) * D_DIM + lc;

    for (int k0 = 0; k0 < D_DIM; k0 += 8) {
        float4 va = *(const float4*)(xp + k0);
        float4 vb = *(const float4*)(wp + k0);
        __syncthreads();
        As[lc + 0][lr] = va.x; As[lc + 1][lr] = va.y;
        As[lc + 2][lr] = va.z; As[lc + 3][lr] = va.w;
        Bs[lc + 0][lr] = vb.x; Bs[lc + 1][lr] = vb.y;
        Bs[lc + 2][lr] = vb.z; Bs[lc + 3][lr] = vb.w;
        __syncthreads();
#pragma unroll
        for (int kk = 0; kk < 8; ++kk) {
            float a[8], b[8];
            *(float4*)&a[0] = *(const float4*)&As[kk][(tm << 3) + 0];
            *(float4*)&a[4] = *(const float4*)&As[kk][(tm << 3) + 4];
            *(float4*)&b[0] = *(const float4*)&Bs[kk][(tn << 3) + 0];
            *(float4*)&b[4] = *(const float4*)&Bs[kk][(tn << 3) + 4];
#pragma unroll
            for (int i = 0; i < 8; ++i)
#pragma unroll
                for (int j = 0; j < 8; ++j)
                    acc[i][j] = fmaf(a[i], b[j], acc[i][j]);
        }
    }

    float bias[8];
#pragma unroll
    for (int j = 0; j < 8; ++j) bias[j] = be[fn0 + (tn << 3) + j];

    const int lane = t & 63;
#pragma unroll
    for (int i = 0; i < 8; ++i) {
        float v0 = -INFINITY, v1 = -INFINITY, v2 = -INFINITY;
        int i0 = 0x7fffffff, i1 = 0x7fffffff, i2 = 0x7fffffff;
#pragma unroll
        for (int j = 0; j < 8; ++j) {
            float v = acc[i][j] + bias[j];
            int c = fn0 + (tn << 3) + j;
            ins3(v, c, v0, i0, v1, i1, v2, i2);
        }
        // merge across the 16 tn-lanes (low 4 bits of lane)
#pragma unroll
        for (int m = 1; m < 16; m <<= 1) {
            float w0 = __shfl_xor(v0, m), w1 = __shfl_xor(v1, m), w2 = __shfl_xor(v2, m);
            int   j0 = __shfl_xor(i0, m), j1 = __shfl_xor(i1, m), j2 = __shfl_xor(i2, m);
            ins3(w0, j0, v0, i0, v1, i1, v2, i2);
            ins3(w1, j1, v0, i0, v1, i1, v2, i2);
            ins3(w2, j2, v0, i0, v1, i1, v2, i2);
        }
        if ((lane & 15) == 0) {
            int row = bm0 + (tm << 3) + i;
            size_t base = ((size_t)row * NTILE + blockIdx.x) * 3;
            pvals[base + 0] = v0; pvals[base + 1] = v1; pvals[base + 2] = v2;
            pidx[base + 0] = i0; pidx[base + 1] = i1; pidx[base + 2] = i2;
        }
    }
}

// ---------------------------------------------------------------------------
// Kernel 2: merge 128 tiles x 3 partials -> global top-3 per row (1 wave/row)
// ---------------------------------------------------------------------------
__global__ __launch_bounds__(64) void topk_merge_kernel(
    const float* __restrict__ pvals, const int* __restrict__ pidx,
    float* __restrict__ vals, int* __restrict__ idxv)
{
    const int row = blockIdx.x;
    const int lane = threadIdx.x;
    float v0 = -INFINITY, v1 = -INFINITY, v2 = -INFINITY;
    int i0 = 0x7fffffff, i1 = 0x7fffffff, i2 = 0x7fffffff;
    size_t base = (size_t)row * NTILE * 3;
#pragma unroll
    for (int m = 0; m < 6; ++m) {  // 384 candidates / 64 lanes
        int j = lane + (m << 6);
        ins3(pvals[base + j], pidx[base + j], v0, i0, v1, i1, v2, i2);
    }
#pragma unroll
    for (int m = 1; m < 64; m <<= 1) {
        float w0 = __shfl_xor(v0, m), w1 = __shfl_xor(v1, m), w2 = __shfl_xor(v2, m);
        int   j0 = __shfl_xor(i0, m), j1 = __shfl_xor(i1, m), j2 = __shfl_xor(i2, m);
        ins3(w0, j0, v0, i0, v1, i1, v2, i2);
        ins3(w1, j1, v0, i0, v1, i1, v2, i2);
        ins3(w2, j2, v0, i0, v1, i1, v2, i2);
    }
    if (lane == 0) {
        vals[row * 3 + 0] = v0; vals[row * 3 + 1] = v1; vals[row * 3 + 2] = v2;
        idxv[row * 3 + 0] = i0; idxv[row * 3 + 1] = i1; idxv[row * 3 + 2] = i2;
    }
}

// ---------------------------------------------------------------------------
// Kernel 3: Gram vectors pp, p1, p2, s11, s22 over all F (coalesced in f)
// ---------------------------------------------------------------------------
__global__ __launch_bounds__(256) void gram_kernel(
    const float* __restrict__ Wd, const float* __restrict__ Wd1,
    const float* __restrict__ Wd2, float* __restrict__ gram)
{
    const int f = blockIdx.x * 256 + threadIdx.x;
    float pp = 0, p1 = 0, p2 = 0, s11 = 0, s22 = 0;
    for (int dd = 0; dd < D_DIM; ++dd) {
        size_t off = (size_t)dd * F_DIM + f;
        float wd = Wd[off], w1 = Wd1[off], w2 = Wd2[off];
        pp  = fmaf(wd, wd, pp);
        p1  = fmaf(wd, w1, p1);
        p2  = fmaf(wd, w2, p2);
        s11 = fmaf(w1, w1, s11);
        s22 = fmaf(w2, w2, s22);
    }
    gram[f] = pp;
    gram[F_DIM + f] = p1;
    gram[2 * F_DIM + f] = p2;
    gram[3 * F_DIM + f] = s11;
    gram[4 * F_DIM + f] = s22;
}

// ---------------------------------------------------------------------------
// Kernel 4: per (b,k) pair: child pre-activations via direct dot, winner,
// c value, and live-latent flags. One wave per pair.
// ---------------------------------------------------------------------------
__global__ __launch_bounds__(256) void child_kernel(
    const float* __restrict__ x,
    const float* __restrict__ We1, const float* __restrict__ be1,
    const float* __restrict__ We2, const float* __restrict__ be2,
    const float* __restrict__ vals, const int* __restrict__ idxv,
    float* __restrict__ cvals, int* __restrict__ wflag,
    int* __restrict__ flagP, int* __restrict__ flag1, int* __restrict__ flag2)
{
    const int pair = (blockIdx.x << 2) + (threadIdx.x >> 6);
    const int lane = threadIdx.x & 63;
    const int b = pair / 3;
    const int f = idxv[pair];
    const float a = vals[pair];
    const float* xb = x + (size_t)b * D_DIM;
    const float* w1 = We1 + (size_t)f * D_DIM;
    const float* w2 = We2 + (size_t)f * D_DIM;
    float s1 = 0.f, s2 = 0.f;
#pragma unroll
    for (int m = 0; m < 8; ++m) {
        int e = lane + (m << 6);
        float xv = xb[e];
        s1 = fmaf(xv, w1[e], s1);
        s2 = fmaf(xv, w2[e], s2);
    }
#pragma unroll
    for (int m = 1; m < 64; m <<= 1) { s1 += __shfl_xor(s1, m); s2 += __shfl_xor(s2, m); }
    if (lane == 0) {
        float p1v = s1 + be1[f];
        float p2v = s2 + be2[f];
        float m1 = (a != 0.f) ? p1v : 0.f;
        float m2 = (a != 0.f) ? p2v : 0.f;
        bool win = m1 > m2;
        float fa1 = win ? m1 : 0.f;
        float fa2 = win ? 0.f : m2;
        cvals[pair] = win ? fa1 : fa2;
        wflag[pair] = win ? 1 : 0;
        flagP[f] = 1;
        if (fa1 != 0.f) flag1[f] = 1;
        if (fa2 != 0.f) flag2[f] = 1;
    }
}

// ---------------------------------------------------------------------------
// Kernel 5: recon[b,:] = bd+bd1+bd2 + sum_k a*Wd[:,f] + c*(win?Wd1:Wd2)[:,f]
// ---------------------------------------------------------------------------
__global__ __launch_bounds__(512) void recon_kernel(
    const float* __restrict__ Wd, const float* __restrict__ bd,
    const float* __restrict__ Wd1, const float* __restrict__ bd1,
    const float* __restrict__ Wd2, const float* __restrict__ bd2,
    const float* __restrict__ vals, const int* __restrict__ idxv,
    const float* __restrict__ cvals, const int* __restrict__ wflag,
    float* __restrict__ out)
{
    const int b = blockIdx.x;
    const int d = threadIdx.x;
    float o = bd[d] + bd1[d] + bd2[d];
#pragma unroll
    for (int k = 0; k < 3; ++k) {
        const int p = b * 3 + k;
        const int f = idxv[p];
        const float a = vals[p];
        const float c = cvals[p];
        const int win = wflag[p];
        const size_t off = (size_t)d * F_DIM + f;
        o = fmaf(a, Wd[off], o);
        if (c != 0.f) o = fmaf(c, win ? Wd1[off] : Wd2[off], o);
    }
    out[(size_t)b * D_DIM + d] = o;
}

// ---------------------------------------------------------------------------
// Kernel 6: aux cosine terms per pair; deterministic per-block partials
// ---------------------------------------------------------------------------
__global__ __launch_bounds__(256) void aux_kernel(
    const float* __restrict__ vals, const float* __restrict__ cvals,
    const int* __restrict__ wflag, const int* __restrict__ idxv,
    const float* __restrict__ gram,
    float* __restrict__ auxpart, float* __restrict__ cntpart)
{
    const int p = blockIdx.x * 256 + threadIdx.x;
    float term = 0.f, act = 0.f;
    {
        const float a = vals[p];
        const float c = cvals[p];
        const int win = wflag[p];
        const int f = idxv[p];
        const float pp = gram[f];
        const float pc = win ? gram[F_DIM + f] : gram[2 * F_DIM + f];
        const float cc = win ? gram[3 * F_DIM + f] : gram[4 * F_DIM + f];
        const float dot = a * (a * pp + c * pc);
        const float nx = fabsf(a) * sqrtf(pp);
        const float ny2 = a * a * pp + 2.f * a * c * pc + c * c * cc;
        const float ny = sqrtf(fmaxf(ny2, 0.f));
        const float cosv = dot / (fmaxf(nx, 1e-8f) * fmaxf(ny, 1e-8f));
        if (a > 0.f) { act = 1.f; term = fmaxf(0.f, 0.7f - cosv); }
    }
#pragma unroll
    for (int m = 1; m < 64; m <<= 1) { term += __shfl_xor(term, m); act += __shfl_xor(act, m); }
    __shared__ float st[2][4];
    const int w = threadIdx.x >> 6;
    if ((threadIdx.x & 63) == 0) { st[0][w] = term; st[1][w] = act; }
    __syncthreads();
    if (threadIdx.x == 0) {
        auxpart[blockIdx.x] = st[0][0] + st[0][1] + st[0][2] + st[0][3];
        cntpart[blockIdx.x] = st[1][0] + st[1][1] + st[1][2] + st[1][3];
    }
}

// ---------------------------------------------------------------------------
// Kernel 7: count flags, finish aux, write scalar outputs (as f32)
// ---------------------------------------------------------------------------
__global__ __launch_bounds__(256) void finalize_kernel(
    const int* __restrict__ flagP, const int* __restrict__ flag1,
    const int* __restrict__ flag2,
    const float* __restrict__ auxpart, const float* __restrict__ cntpart,
    float* __restrict__ out)
{
    const int t = threadIdx.x;
    int sp = 0, s1 = 0, s2 = 0;
    for (int f = t; f < F_DIM; f += 256) { sp += flagP[f]; s1 += flag1[f]; s2 += flag2[f]; }
#pragma unroll
    for (int m = 1; m < 64; m <<= 1) {
        sp += __shfl_xor(sp, m); s1 += __shfl_xor(s1, m); s2 += __shfl_xor(s2, m);
    }
    __shared__ int red[3][4];
    const int w = t >> 6;
    if ((t & 63) == 0) { red[0][w] = sp; red[1][w] = s1; red[2][w] = s2; }
    __syncthreads();
    if (t == 0) {
        float np_ = (float)(red[0][0] + red[0][1] + red[0][2] + red[0][3]);
        float n1_ = (float)(red[1][0] + red[1][1] + red[1][2] + red[1][3]);
        float n2_ = (float)(red[2][0] + red[2][1] + red[2][2] + red[2][3]);
        float asum = 0.f, acnt = 0.f;
        for (int i = 0; i < 24; ++i) { asum += auxpart[i]; acnt += cntpart[i]; }
        const size_t base = (size_t)B_DIM * D_DIM;
        out[base + 0] = np_;
        out[base + 1] = n1_;
        out[base + 2] = n2_;
        out[base + 3] = asum / (acnt + 1e-8f);
    }
}

extern "C" void kernel_launch(void* const* d_in, const int* in_sizes, int n_in,
                              void* d_out, int out_size, void* d_ws, size_t ws_size,
                              hipStream_t stream)
{
    (void)in_sizes; (void)n_in; (void)out_size; (void)ws_size;
    const float* x   = (const float*)d_in[0];
    const float* We  = (const float*)d_in[1];
    const float* be  = (const float*)d_in[2];
    const float* Wd  = (const float*)d_in[3];
    const float* bd  = (const float*)d_in[4];
    const float* We1 = (const float*)d_in[5];
    const float* be1 = (const float*)d_in[6];
    const float* Wd1 = (const float*)d_in[7];
    const float* bd1 = (const float*)d_in[8];
    const float* We2 = (const float*)d_in[9];
    const float* be2 = (const float*)d_in[10];
    const float* Wd2 = (const float*)d_in[11];
    const float* bd2 = (const float*)d_in[12];
    float* out = (float*)d_out;

    // workspace layout (all 4-byte aligned)
    int*   flagP = (int*)d_ws;                                    // F
    int*   flag1 = flagP + F_DIM;                                 // F
    int*   flag2 = flag1 + F_DIM;                                 // F
    float* gram  = (float*)(flag2 + F_DIM);                       // 5F
    float* pvals = gram + 5 * F_DIM;                              // B*NTILE*3
    int*   pidx  = (int*)(pvals + (size_t)B_DIM * NTILE * 3);     // B*NTILE*3
    float* vals  = (float*)(pidx + (size_t)B_DIM * NTILE * 3);    // B*3
    int*   idxv  = (int*)(vals + B_DIM * 3);                      // B*3
    float* cvals = (float*)(idxv + B_DIM * 3);                    // B*3
    int*   wflag = (int*)(cvals + B_DIM * 3);                     // B*3
    float* auxpart = (float*)(wflag + B_DIM * 3);                 // 24
    float* cntpart = auxpart + 24;                                // 24

    // zero the flag arrays (must happen every call — harness does not re-poison)
    hipMemsetAsync(flagP, 0, 3 * F_DIM * sizeof(int), stream);

    dim3 g1(NTILE, B_DIM / 128);  // 128 x 16 = 2048 blocks
    enc_topk_kernel<<<g1, 256, 0, stream>>>(x, We, be, pvals, pidx);
    topk_merge_kernel<<<B_DIM, 64, 0, stream>>>(pvals, pidx, vals, idxv);
    gram_kernel<<<F_DIM / 256, 256, 0, stream>>>(Wd, Wd1, Wd2, gram);
    child_kernel<<<(B_DIM * K_TOP) / 4, 256, 0, stream>>>(
        x, We1, be1, We2, be2, vals, idxv, cvals, wflag, flagP, flag1, flag2);
    recon_kernel<<<B_DIM, 512, 0, stream>>>(
        Wd, bd, Wd1, bd1, Wd2, bd2, vals, idxv, cvals, wflag, out);
    aux_kernel<<<(B_DIM * K_TOP) / 256, 256, 0, stream>>>(
        vals, cvals, wflag, idxv, gram, auxpart, cntpart);
    finalize_kernel<<<1, 256, 0, stream>>>(flagP, flag1, flag2, auxpart, cntpart, out);
}

// Round 2
// 628.042 us; speedup vs baseline: 1.2036x; 1.2036x over previous
//
#include <hip/hip_runtime.h>
#include <math.h>

#define B_DIM 2048
#define D_DIM 512
#define F_DIM 16384
#define K_TOP 3

typedef __attribute__((ext_vector_type(8))) short bf16x8;
typedef __attribute__((ext_vector_type(4))) float f32x4;

#define GL16(gsrc, ldst) \
  __builtin_amdgcn_global_load_lds( \
      (__attribute__((address_space(1))) const void*)(gsrc), \
      (__attribute__((address_space(3))) void*)(ldst), 16, 0, 0)

// lexicographic "better": larger value wins; tie -> lower index (lax.top_k)
__device__ __forceinline__ bool better(float v, int c, float w, int j) {
    return (v > w) || (v == w && c < j);
}

__device__ __forceinline__ void ins3(float v, int c,
    float& v0, int& i0, float& v1, int& i1, float& v2, int& i2)
{
    if (!better(v, c, v2, i2)) return;
    if (better(v, c, v1, i1)) {
        v2 = v1; i2 = i1;
        if (better(v, c, v0, i0)) { v1 = v0; i1 = i0; v0 = v; i0 = c; }
        else { v1 = v; i1 = c; }
    } else { v2 = v; i2 = c; }
}

// bubble-insert into a descending top-N kept in registers (static indices only)
template <int N>
__device__ __forceinline__ void insN(float v, int c, float* V, int* I) {
#pragma unroll
    for (int k = 0; k < N; ++k) {
        bool b = better(v, c, V[k], I[k]);
        float tv = V[k]; int ti = I[k];
        if (b) { V[k] = v; I[k] = c; v = tv; c = ti; }
    }
}

// ---------------------------------------------------------------------------
// Kernel 0: f32 -> bf16 (truncation), 8 elems/thread/iter
// ---------------------------------------------------------------------------
__global__ __launch_bounds__(256) void convert_kernel(
    const float* __restrict__ src, ushort* __restrict__ dst, int n8)
{
    int i = blockIdx.x * 256 + threadIdx.x;
    const int stride = gridDim.x * 256;
    for (; i < n8; i += stride) {
        float4 a = ((const float4*)src)[i * 2];
        float4 b = ((const float4*)src)[i * 2 + 1];
        uint4 o;
        o.x = (__float_as_uint(a.y) & 0xFFFF0000u) | (__float_as_uint(a.x) >> 16);
        o.y = (__float_as_uint(a.w) & 0xFFFF0000u) | (__float_as_uint(a.z) >> 16);
        o.z = (__float_as_uint(b.y) & 0xFFFF0000u) | (__float_as_uint(b.x) >> 16);
        o.w = (__float_as_uint(b.w) & 0xFFFF0000u) | (__float_as_uint(b.z) >> 16);
        ((uint4*)dst)[i] = o;
    }
}

// ---------------------------------------------------------------------------
// Kernel 1: bf16 MFMA GEMM pre = x @ We^T (+be), fused per-(row,128-tile)
// top-4 screen. 128x128 tile, BK=32, 256 threads (4 waves, 2x2), m97-style
// global_load_lds staging. Output: packed f32 val with local col in low 7
// mantissa bits -> packed[row][tile*4 + j].
// ---------------------------------------------------------------------------
__global__ __launch_bounds__(256) void enc_mfma_kernel(
    const ushort* __restrict__ xb, const ushort* __restrict__ web,
    const float* __restrict__ be, uint* __restrict__ packed)
{
    __shared__ __align__(16) ushort As[128 * 32];
    __shared__ __align__(16) ushort Bs[128 * 32];
    __shared__ float eps[16][132];
    __shared__ float mval[4][16][4];
    __shared__ int   midx[4][16][4];

    const int t = threadIdx.x;
    const int l = t & 63;
    const int w = t >> 6;        // wave id
    const int wr = w >> 1;       // 0,1
    const int wc = w & 1;        // 0,1
    const int bm0 = blockIdx.y << 7;
    const int fn0 = blockIdx.x << 7;

    f32x4 acc[4][4];
#pragma unroll
    for (int m = 0; m < 4; ++m)
#pragma unroll
        for (int n = 0; n < 4; ++n) acc[m][n] = (f32x4)(0.f);

    // staging addresses: linear LDS [row][32 kcols] bf16; 2 issues each for A,B
    const int sr = t >> 2;             // 0..63
    const int sc = (t & 3) << 3;       // 0,8,16,24
    const ushort* gA0 = xb + (bm0 + sr) * D_DIM + sc;
    const ushort* gA1 = xb + (bm0 + 64 + sr) * D_DIM + sc;
    const ushort* gB0 = web + (size_t)(fn0 + sr) * D_DIM + sc;
    const ushort* gB1 = web + (size_t)(fn0 + 64 + sr) * D_DIM + sc;
    char* lA0 = (char*)As + t * 16;
    char* lA1 = (char*)As + 4096 + t * 16;
    char* lB0 = (char*)Bs + t * 16;
    char* lB1 = (char*)Bs + 4096 + t * 16;

    const int frow = l & 15;       // fragment row/col lane part
    const int fkc = (l >> 4) << 3; // k-chunk*8

    for (int k0 = 0; k0 < D_DIM; k0 += 32) {
        GL16(gA0 + k0, lA0);
        GL16(gA1 + k0, lA1);
        GL16(gB0 + k0, lB0);
        GL16(gB1 + k0, lB1);
        __syncthreads();   // drains vmcnt -> staging visible
        bf16x8 af[4], bfr[4];
#pragma unroll
        for (int m = 0; m < 4; ++m)
            af[m] = *(const bf16x8*)&As[(wr * 64 + m * 16 + frow) * 32 + fkc];
#pragma unroll
        for (int n = 0; n < 4; ++n)
            bfr[n] = *(const bf16x8*)&Bs[(wc * 64 + n * 16 + frow) * 32 + fkc];
#pragma unroll
        for (int m = 0; m < 4; ++m)
#pragma unroll
            for (int n = 0; n < 4; ++n)
                acc[m][n] = __builtin_amdgcn_mfma_f32_16x16x32_bf16(
                    af[m], bfr[n], acc[m][n], 0, 0, 0);
        __syncthreads();   // all waves done reading before next overwrite
    }

    // add bias (col = fn0 + wc*64 + n*16 + frow)
    float bias[4];
#pragma unroll
    for (int n = 0; n < 4; ++n) bias[n] = be[fn0 + wc * 64 + n * 16 + frow];
#pragma unroll
    for (int m = 0; m < 4; ++m)
#pragma unroll
        for (int n = 0; n < 4; ++n)
#pragma unroll
            for (int i = 0; i < 4; ++i) acc[m][n][i] += bias[n];

    // epilogue: 8 chunks of 16 rows; C/D layout col=l&15, row=(l>>4)*4+reg
    const int wrow4 = (l >> 4) << 2;
#pragma unroll 1
    for (int g = 0; g < 8; ++g) {
        __syncthreads();
        if (wr == (g >> 2)) {
            const int m = g & 3;
#pragma unroll
            for (int n = 0; n < 4; ++n)
#pragma unroll
                for (int i = 0; i < 4; ++i)
                    eps[wrow4 + i][wc * 64 + n * 16 + frow] = acc[m][n][i];
        }
        __syncthreads();
        // scan: thread t covers row (t&15), cols (t>>4)*8 .. +7
        const int row = t & 15, seg = t >> 4;
        float V[4]; int I[4];
#pragma unroll
        for (int j = 0; j < 4; ++j) { V[j] = -INFINITY; I[j] = 0x7fffffff; }
#pragma unroll
        for (int c = 0; c < 8; ++c) {
            int col = seg * 8 + c;
            insN<4>(eps[row][col], col, V, I);
        }
        // merge the 4 lanes of this wave sharing the row (xor bits 4,5)
#pragma unroll
        for (int mk = 16; mk <= 32; mk <<= 1) {
            float t0 = __shfl_xor(V[0], mk), t1 = __shfl_xor(V[1], mk);
            float t2 = __shfl_xor(V[2], mk), t3 = __shfl_xor(V[3], mk);
            int u0 = __shfl_xor(I[0], mk), u1 = __shfl_xor(I[1], mk);
            int u2 = __shfl_xor(I[2], mk), u3 = __shfl_xor(I[3], mk);
            insN<4>(t0, u0, V, I); insN<4>(t1, u1, V, I);
            insN<4>(t2, u2, V, I); insN<4>(t3, u3, V, I);
        }
        if (l < 16) {
#pragma unroll
            for (int j = 0; j < 4; ++j) { mval[w][row][j] = V[j]; midx[w][row][j] = I[j]; }
        }
        __syncthreads();
        if (t < 16) {   // final cross-wave merge, one thread per row
            float V2[4]; int I2[4];
#pragma unroll
            for (int j = 0; j < 4; ++j) { V2[j] = -INFINITY; I2[j] = 0x7fffffff; }
#pragma unroll
            for (int q = 0; q < 4; ++q)
#pragma unroll
                for (int j = 0; j < 4; ++j) insN<4>(mval[q][t][j], midx[q][t][j], V2, I2);
            uint* dst = packed + ((size_t)(bm0 + g * 16 + t) << 9) + (blockIdx.x << 2);
#pragma unroll
            for (int j = 0; j < 4; ++j)
                dst[j] = (__float_as_uint(V2[j]) & 0xFFFFFF80u) | (uint)I2[j];
        }
    }
}

// ---------------------------------------------------------------------------
// Kernel 2: merge 128 tiles x 4 packed -> global top-8 candidates per row
// ---------------------------------------------------------------------------
__global__ __launch_bounds__(64) void topk8_merge_kernel(
    const uint* __restrict__ packed, int* __restrict__ c8i)
{
    const int row = blockIdx.x;
    const int l = threadIdx.x;
    float V[8]; int I[8];
#pragma unroll
    for (int j = 0; j < 8; ++j) { V[j] = -INFINITY; I[j] = 0x7fffffff; }
    const uint* p = packed + ((size_t)row << 9);
#pragma unroll
    for (int m = 0; m < 8; ++m) {
        int pos = l + (m << 6);
        uint u = p[pos];
        float v = __uint_as_float(u & 0xFFFFFF80u);
        int gidx = ((pos >> 2) << 7) | (int)(u & 0x7Fu);
        insN<8>(v, gidx, V, I);
    }
#pragma unroll
    for (int mk = 1; mk < 64; mk <<= 1) {
        float wv[8]; int wi[8];
#pragma unroll
        for (int j = 0; j < 8; ++j) { wv[j] = __shfl_xor(V[j], mk); wi[j] = __shfl_xor(I[j], mk); }
#pragma unroll
        for (int j = 0; j < 8; ++j) insN<8>(wv[j], wi[j], V, I);
    }
    if (l == 0) {
#pragma unroll
        for (int j = 0; j < 8; ++j) c8i[row * 8 + j] = I[j];
    }
}

// ---------------------------------------------------------------------------
// Kernel 3: exact f32 refinement of the 8 candidates + lex top-3 select
// ---------------------------------------------------------------------------
__global__ __launch_bounds__(512) void refine_kernel(
    const float* __restrict__ x, const float* __restrict__ We,
    const float* __restrict__ be, const int* __restrict__ c8i,
    float* __restrict__ vals, int* __restrict__ idxv)
{
    const int row = blockIdx.x;
    const int wv = threadIdx.x >> 6, l = threadIdx.x & 63;
    const int f = c8i[row * 8 + wv];
    const float* xr = x + (size_t)row * D_DIM;
    const float* wp = We + (size_t)f * D_DIM;
    float s = 0.f;
#pragma unroll
    for (int m = 0; m < 8; ++m) { int e = l + (m << 6); s = fmaf(xr[e], wp[e], s); }
#pragma unroll
    for (int mk = 1; mk < 64; mk <<= 1) s += __shfl_xor(s, mk);
    __shared__ float sv[8];
    __shared__ int si[8];
    if (l == 0) { sv[wv] = s + be[f]; si[wv] = f; }
    __syncthreads();
    if (threadIdx.x == 0) {
        float v0 = -INFINITY, v1 = -INFINITY, v2 = -INFINITY;
        int i0 = 0x7fffffff, i1 = 0x7fffffff, i2 = 0x7fffffff;
        for (int k = 0; k < 8; ++k) ins3(sv[k], si[k], v0, i0, v1, i1, v2, i2);
        vals[row * 3 + 0] = v0; idxv[row * 3 + 0] = i0;
        vals[row * 3 + 1] = v1; idxv[row * 3 + 1] = i1;
        vals[row * 3 + 2] = v2; idxv[row * 3 + 2] = i2;
    }
}

// ---------------------------------------------------------------------------
// Kernel 4: Gram vectors pp, p1, p2, s11, s22 over all F (coalesced in f)
// ---------------------------------------------------------------------------
__global__ __launch_bounds__(256) void gram_kernel(
    const float* __restrict__ Wd, const float* __restrict__ Wd1,
    const float* __restrict__ Wd2, float* __restrict__ gram)
{
    const int f = blockIdx.x * 256 + threadIdx.x;
    float pp = 0, p1 = 0, p2 = 0, s11 = 0, s22 = 0;
    for (int dd = 0; dd < D_DIM; ++dd) {
        size_t off = (size_t)dd * F_DIM + f;
        float wd = Wd[off], w1 = Wd1[off], w2 = Wd2[off];
        pp  = fmaf(wd, wd, pp);
        p1  = fmaf(wd, w1, p1);
        p2  = fmaf(wd, w2, p2);
        s11 = fmaf(w1, w1, s11);
        s22 = fmaf(w2, w2, s22);
    }
    gram[f] = pp;
    gram[F_DIM + f] = p1;
    gram[2 * F_DIM + f] = p2;
    gram[3 * F_DIM + f] = s11;
    gram[4 * F_DIM + f] = s22;
}

// ---------------------------------------------------------------------------
// Kernel 5: per (b,k): child pre-acts (exact f32 dot), winner, c, flags
// ---------------------------------------------------------------------------
__global__ __launch_bounds__(256) void child_kernel(
    const float* __restrict__ x,
    const float* __restrict__ We1, const float* __restrict__ be1,
    const float* __restrict__ We2, const float* __restrict__ be2,
    const float* __restrict__ vals, const int* __restrict__ idxv,
    float* __restrict__ cvals, int* __restrict__ wflag,
    int* __restrict__ flagP, int* __restrict__ flag1, int* __restrict__ flag2)
{
    const int pair = (blockIdx.x << 2) + (threadIdx.x >> 6);
    const int lane = threadIdx.x & 63;
    const int b = pair / 3;
    const int f = idxv[pair];
    const float a = vals[pair];
    const float* xb = x + (size_t)b * D_DIM;
    const float* w1 = We1 + (size_t)f * D_DIM;
    const float* w2 = We2 + (size_t)f * D_DIM;
    float s1 = 0.f, s2 = 0.f;
#pragma unroll
    for (int m = 0; m < 8; ++m) {
        int e = lane + (m << 6);
        float xv = xb[e];
        s1 = fmaf(xv, w1[e], s1);
        s2 = fmaf(xv, w2[e], s2);
    }
#pragma unroll
    for (int m = 1; m < 64; m <<= 1) { s1 += __shfl_xor(s1, m); s2 += __shfl_xor(s2, m); }
    if (lane == 0) {
        float p1v = s1 + be1[f];
        float p2v = s2 + be2[f];
        float m1 = (a != 0.f) ? p1v : 0.f;
        float m2 = (a != 0.f) ? p2v : 0.f;
        bool win = m1 > m2;
        float fa1 = win ? m1 : 0.f;
        float fa2 = win ? 0.f : m2;
        cvals[pair] = win ? fa1 : fa2;
        wflag[pair] = win ? 1 : 0;
        flagP[f] = 1;
        if (fa1 != 0.f) flag1[f] = 1;
        if (fa2 != 0.f) flag2[f] = 1;
    }
}

// ---------------------------------------------------------------------------
// Kernel 6: recon[b,:] = biases + sum_k a*Wd[:,f] + c*(win?Wd1:Wd2)[:,f]
// ---------------------------------------------------------------------------
__global__ __launch_bounds__(512) void recon_kernel(
    const float* __restrict__ Wd, const float* __restrict__ bd,
    const float* __restrict__ Wd1, const float* __restrict__ bd1,
    const float* __restrict__ Wd2, const float* __restrict__ bd2,
    const float* __restrict__ vals, const int* __restrict__ idxv,
    const float* __restrict__ cvals, const int* __restrict__ wflag,
    float* __restrict__ out)
{
    const int b = blockIdx.x;
    const int d = threadIdx.x;
    float o = bd[d] + bd1[d] + bd2[d];
#pragma unroll
    for (int k = 0; k < 3; ++k) {
        const int p = b * 3 + k;
        const int f = idxv[p];
        const float a = vals[p];
        const float c = cvals[p];
        const int win = wflag[p];
        const size_t off = (size_t)d * F_DIM + f;
        o = fmaf(a, Wd[off], o);
        if (c != 0.f) o = fmaf(c, win ? Wd1[off] : Wd2[off], o);
    }
    out[(size_t)b * D_DIM + d] = o;
}

// ---------------------------------------------------------------------------
// Kernel 7: aux cosine terms per pair; deterministic per-block partials
// ---------------------------------------------------------------------------
__global__ __launch_bounds__(256) void aux_kernel(
    const float* __restrict__ vals, const float* __restrict__ cvals,
    const int* __restrict__ wflag, const int* __restrict__ idxv,
    const float* __restrict__ gram,
    float* __restrict__ auxpart, float* __restrict__ cntpart)
{
    const int p = blockIdx.x * 256 + threadIdx.x;
    float term = 0.f, act = 0.f;
    {
        const float a = vals[p];
        const float c = cvals[p];
        const int win = wflag[p];
        const int f = idxv[p];
        const float pp = gram[f];
        const float pc = win ? gram[F_DIM + f] : gram[2 * F_DIM + f];
        const float cc = win ? gram[3 * F_DIM + f] : gram[4 * F_DIM + f];
        const float dot = a * (a * pp + c * pc);
        const float nx = fabsf(a) * sqrtf(pp);
        const float ny2 = a * a * pp + 2.f * a * c * pc + c * c * cc;
        const float ny = sqrtf(fmaxf(ny2, 0.f));
        const float cosv = dot / (fmaxf(nx, 1e-8f) * fmaxf(ny, 1e-8f));
        if (a > 0.f) { act = 1.f; term = fmaxf(0.f, 0.7f - cosv); }
    }
#pragma unroll
    for (int m = 1; m < 64; m <<= 1) { term += __shfl_xor(term, m); act += __shfl_xor(act, m); }
    __shared__ float st[2][4];
    const int w = threadIdx.x >> 6;
    if ((threadIdx.x & 63) == 0) { st[0][w] = term; st[1][w] = act; }
    __syncthreads();
    if (threadIdx.x == 0) {
        auxpart[blockIdx.x] = st[0][0] + st[0][1] + st[0][2] + st[0][3];
        cntpart[blockIdx.x] = st[1][0] + st[1][1] + st[1][2] + st[1][3];
    }
}

// ---------------------------------------------------------------------------
// Kernel 8: count flags, finish aux, write scalar outputs (as f32)
// ---------------------------------------------------------------------------
__global__ __launch_bounds__(256) void finalize_kernel(
    const int* __restrict__ flagP, const int* __restrict__ flag1,
    const int* __restrict__ flag2,
    const float* __restrict__ auxpart, const float* __restrict__ cntpart,
    float* __restrict__ out)
{
    const int t = threadIdx.x;
    int sp = 0, s1 = 0, s2 = 0;
    for (int f = t; f < F_DIM; f += 256) { sp += flagP[f]; s1 += flag1[f]; s2 += flag2[f]; }
#pragma unroll
    for (int m = 1; m < 64; m <<= 1) {
        sp += __shfl_xor(sp, m); s1 += __shfl_xor(s1, m); s2 += __shfl_xor(s2, m);
    }
    __shared__ int red[3][4];
    const int w = t >> 6;
    if ((t & 63) == 0) { red[0][w] = sp; red[1][w] = s1; red[2][w] = s2; }
    __syncthreads();
    if (t == 0) {
        float np_ = (float)(red[0][0] + red[0][1] + red[0][2] + red[0][3]);
        float n1_ = (float)(red[1][0] + red[1][1] + red[1][2] + red[1][3]);
        float n2_ = (float)(red[2][0] + red[2][1] + red[2][2] + red[2][3]);
        float asum = 0.f, acnt = 0.f;
        for (int i = 0; i < 24; ++i) { asum += auxpart[i]; acnt += cntpart[i]; }
        const size_t base = (size_t)B_DIM * D_DIM;
        out[base + 0] = np_;
        out[base + 1] = n1_;
        out[base + 2] = n2_;
        out[base + 3] = asum / (acnt + 1e-8f);
    }
}

extern "C" void kernel_launch(void* const* d_in, const int* in_sizes, int n_in,
                              void* d_out, int out_size, void* d_ws, size_t ws_size,
                              hipStream_t stream)
{
    (void)in_sizes; (void)n_in; (void)out_size; (void)ws_size;
    const float* x   = (const float*)d_in[0];
    const float* We  = (const float*)d_in[1];
    const float* be  = (const float*)d_in[2];
    const float* Wd  = (const float*)d_in[3];
    const float* bd  = (const float*)d_in[4];
    const float* We1 = (const float*)d_in[5];
    const float* be1 = (const float*)d_in[6];
    const float* Wd1 = (const float*)d_in[7];
    const float* bd1 = (const float*)d_in[8];
    const float* We2 = (const float*)d_in[9];
    const float* be2 = (const float*)d_in[10];
    const float* Wd2 = (const float*)d_in[11];
    const float* bd2 = (const float*)d_in[12];
    float* out = (float*)d_out;

    // workspace layout (16B-aligned chunks), total ~23.6 MB
    ushort* x_bf  = (ushort*)d_ws;                            // B*D bf16
    ushort* We_bf = x_bf + (size_t)B_DIM * D_DIM;             // F*D bf16
    uint*   packed = (uint*)(We_bf + (size_t)F_DIM * D_DIM);  // B*512
    float*  gram  = (float*)(packed + (size_t)B_DIM * 512);   // 5F
    int*    flagP = (int*)(gram + 5 * F_DIM);                 // F
    int*    flag1 = flagP + F_DIM;                            // F
    int*    flag2 = flag1 + F_DIM;                            // F
    int*    c8i   = flag2 + F_DIM;                            // B*8
    float*  vals  = (float*)(c8i + B_DIM * 8);                // B*3
    int*    idxv  = (int*)(vals + B_DIM * 3);                 // B*3
    float*  cvals = (float*)(idxv + B_DIM * 3);               // B*3
    int*    wflag = (int*)(cvals + B_DIM * 3);                // B*3
    float*  auxpart = (float*)(wflag + B_DIM * 3);            // 24
    float*  cntpart = auxpart + 24;                           // 24

    hipMemsetAsync(flagP, 0, 3 * F_DIM * sizeof(int), stream);

    convert_kernel<<<2048, 256, 0, stream>>>(We, We_bf, F_DIM * D_DIM / 8);
    convert_kernel<<<256, 256, 0, stream>>>(x, x_bf, B_DIM * D_DIM / 8);

    dim3 g1(F_DIM / 128, B_DIM / 128);  // 128 x 16
    enc_mfma_kernel<<<g1, 256, 0, stream>>>(x_bf, We_bf, be, packed);
    topk8_merge_kernel<<<B_DIM, 64, 0, stream>>>(packed, c8i);
    refine_kernel<<<B_DIM, 512, 0, stream>>>(x, We, be, c8i, vals, idxv);

    gram_kernel<<<F_DIM / 256, 256, 0, stream>>>(Wd, Wd1, Wd2, gram);
    child_kernel<<<(B_DIM * K_TOP) / 4, 256, 0, stream>>>(
        x, We1, be1, We2, be2, vals, idxv, cvals, wflag, flagP, flag1, flag2);
    recon_kernel<<<B_DIM, 512, 0, stream>>>(
        Wd, bd, Wd1, bd1, Wd2, bd2, vals, idxv, cvals, wflag, out);
    aux_kernel<<<(B_DIM * K_TOP) / 256, 256, 0, stream>>>(
        vals, cvals, wflag, idxv, gram, auxpart, cntpart);
    finalize_kernel<<<1, 256, 0, stream>>>(flagP, flag1, flag2, auxpart, cntpart, out);
}